// Round 2
// baseline (2590.952 us; speedup 1.0000x reference)
//
#include <hip/hip_runtime.h>
#include <stdint.h>

// ---------------- problem constants ----------------
#define NE      16384
#define BATCH   4096
#define DFULL   1024
#define DHALF   512
#define TOPK    10
#define NCHUNK  8
#define CHUNK   2048   // 16384 / 8
#define BETA_C  0.25f

typedef __bf16 bf16x8 __attribute__((ext_vector_type(8)));
typedef float  f32x4  __attribute__((ext_vector_type(4)));

__device__ inline uint16_t f2bf(float f) {
    unsigned u = __float_as_uint(f);
    unsigned r = (u + 0x7FFFu + ((u >> 16) & 1u)) >> 16;
    return (uint16_t)r;
}

__device__ inline void gload16(const uint16_t* g, uint16_t* l) {
    __builtin_amdgcn_global_load_lds(
        (const __attribute__((address_space(1))) void*)(const void*)g,
        (__attribute__((address_space(3))) void*)l, 16, 0, 0);
}

__device__ inline float dot4(float4 a, float4 b) {
    return a.x*b.x + a.y*b.y + a.z*b.z + a.w*b.w;
}

// ---------------- normalization kernels ----------------
// z: [4096,1024]; normalize halves separately; write bf16 + store inv norms
__global__ __launch_bounds__(256) void k_norm_z(const float* __restrict__ z,
                                                uint16_t* __restrict__ zn,
                                                float* __restrict__ rnzt,
                                                float* __restrict__ rnzg) {
    int b = blockIdx.x, t = threadIdx.x;
    const float4* zp = (const float4*)(z + (size_t)b * DFULL);
    float4 v = zp[t];
    float ss = v.x*v.x + v.y*v.y + v.z*v.z + v.w*v.w;
    #pragma unroll
    for (int off = 32; off; off >>= 1) ss += __shfl_xor(ss, off);
    __shared__ float red[4];
    if ((t & 63) == 0) red[t >> 6] = ss;
    __syncthreads();
    float tot = (t < 128) ? (red[0] + red[1]) : (red[2] + red[3]);
    float rn = rsqrtf(tot + 1e-12f);
    if (t == 0)   rnzt[b] = rn;
    if (t == 128) rnzg[b] = rn;
    uint16_t* o = zn + (size_t)b * DFULL + t * 4;
    o[0] = f2bf(v.x * rn); o[1] = f2bf(v.y * rn);
    o[2] = f2bf(v.z * rn); o[3] = f2bf(v.w * rn);
}

// codebook row normalize: [16384,512] -> bf16 at dst (row stride dstld); store rn
__global__ __launch_bounds__(128) void k_norm_cb(const float* __restrict__ w,
                                                 uint16_t* __restrict__ dst, int dstld,
                                                 float* __restrict__ rns) {
    int r = blockIdx.x, t = threadIdx.x;
    const float4* wp = (const float4*)(w + (size_t)r * DHALF);
    float4 v = wp[t];
    float ss = v.x*v.x + v.y*v.y + v.z*v.z + v.w*v.w;
    #pragma unroll
    for (int off = 32; off; off >>= 1) ss += __shfl_xor(ss, off);
    __shared__ float red[2];
    if ((t & 63) == 0) red[t >> 6] = ss;
    __syncthreads();
    float rn = rsqrtf(red[0] + red[1] + 1e-12f);
    if (t == 0) rns[r] = rn;
    uint16_t* o = dst + (size_t)r * dstld + t * 4;
    o[0] = f2bf(v.x * rn); o[1] = f2bf(v.y * rn);
    o[2] = f2bf(v.z * rn); o[3] = f2bf(v.w * rn);
}

// ---------------- fused score GEMM + per-row top-10 screen (bf16) ----------------
// S[row, col] = sum_k An[row, aoff+k] * Bn[col, k]
// grid: (4096/64, NCHUNK); block 256 (4 waves, wave w owns rows 16w..16w+15)
__global__ __launch_bounds__(256) void k_gemm_topk(
    const uint16_t* __restrict__ An, int lda, int aoff,
    const uint16_t* __restrict__ Bn, int ldb, int Kdim,
    float* __restrict__ pv, int* __restrict__ pi)
{
    __shared__ uint16_t Asm[64 * 64];   // 8 KB, XOR-swizzled rows
    __shared__ uint16_t Bsm[64 * 64];   // 8 KB
    __shared__ float topv[4][16][TOPK];
    __shared__ int   topi[4][16][TOPK];
    __shared__ float thr[4][16];

    const int tid  = threadIdx.x;
    const int lane = tid & 63;
    const int wv   = tid >> 6;
    const int rowbase = blockIdx.x * 64;
    const int colbase = blockIdx.y * CHUNK;

    for (int e = lane; e < 16 * TOPK; e += 64) {
        topv[wv][e / TOPK][e % TOPK] = -1e30f;
        topi[wv][e / TOPK][e % TOPK] = 0;
    }
    if (lane < 16) thr[wv][lane] = -1e30f;
    __syncthreads();

    for (int cb = 0; cb < CHUNK; cb += 64) {
        f32x4 zero = {0.f, 0.f, 0.f, 0.f};
        f32x4 acc[4];
        #pragma unroll
        for (int ct = 0; ct < 4; ++ct) acc[ct] = zero;

        for (int kc = 0; kc < Kdim; kc += 64) {
            const uint16_t* Ag = An + (size_t)rowbase * lda + aoff + kc;
            const uint16_t* Bg = Bn + (size_t)(colbase + cb) * ldb + kc;
            #pragma unroll
            for (int it = 0; it < 2; ++it) {
                int q = it * 4 + wv;
                int o = q * 1024 + lane * 16;          // linear LDS byte offset
                int row = o >> 7;
                int kb  = (o & 127) ^ ((row & 7) << 4); // pre-swizzled source (m173)
                gload16(Ag + row * lda + (kb >> 1), &Asm[0] + q * 512);
                gload16(Bg + row * ldb + (kb >> 1), &Bsm[0] + q * 512);
            }
            __syncthreads();
            #pragma unroll
            for (int ks = 0; ks < 2; ++ks) {
                int kb = ks * 64 + ((lane >> 4) * 16);  // byte offset of 8 bf16
                int ra = 16 * wv + (lane & 15);
                const bf16x8 a = *(const bf16x8*)((const char*)Asm +
                                   ra * 128 + (kb ^ ((ra & 7) << 4)));
                #pragma unroll
                for (int ct = 0; ct < 4; ++ct) {
                    int rb = ct * 16 + (lane & 15);
                    const bf16x8 b = *(const bf16x8*)((const char*)Bsm +
                                       rb * 128 + (kb ^ ((rb & 7) << 4)));
                    acc[ct] = __builtin_amdgcn_mfma_f32_16x16x32_bf16(a, b, acc[ct], 0, 0, 0);
                }
            }
            __syncthreads();
        }

        // ---- top-k update: C layout col=lane&15, row=(lane>>4)*4+i ----
        int rloc = (lane >> 4) * 4;
        #pragma unroll
        for (int ct = 0; ct < 4; ++ct) {
            #pragma unroll
            for (int i = 0; i < 4; ++i) {
                float v  = acc[ct][i];
                int   r  = rloc + i;
                int  col = colbase + cb + ct * 16 + (lane & 15);
                float t  = thr[wv][r];
                unsigned long long m = __ballot(v > t);
                while (m) {
                    int l = __ffsll(m) - 1;
                    m &= m - 1;
                    float vv = __shfl(v, l);
                    int   cc = __shfl(col, l);
                    int   rr = __shfl(r, l);
                    if (lane == 0) {
                        float mn = topv[wv][rr][0]; int mp = 0;
                        #pragma unroll
                        for (int j = 1; j < TOPK; ++j) {
                            float x = topv[wv][rr][j];
                            if (x < mn) { mn = x; mp = j; }
                        }
                        if (vv > mn) {
                            topv[wv][rr][mp] = vv; topi[wv][rr][mp] = cc;
                            float nm = topv[wv][rr][0];
                            #pragma unroll
                            for (int j = 1; j < TOPK; ++j) nm = fminf(nm, topv[wv][rr][j]);
                            thr[wv][rr] = nm;
                        }
                    }
                }
            }
        }
    }

    if (lane < TOPK) {
        for (int r = 0; r < 16; ++r) {
            int grow = rowbase + 16 * wv + r;
            size_t o = ((size_t)grow * NCHUNK + blockIdx.y) * TOPK + lane;
            pv[o] = topv[wv][r][lane];
            pi[o] = topi[wv][r][lane];
        }
    }
}

// ---------------- exact rescore + merge + softmax + mix + losses + usage ----------------
// one block (256 thr) per batch row. w0/w1 are ORIGINAL f32 codebooks [NE,512].
__global__ __launch_bounds__(256) void k_merge(
    const float* __restrict__ pv, const int* __restrict__ pi,
    const float* __restrict__ w0, const float* __restrict__ rn0,
    const float* __restrict__ w1, const float* __restrict__ rn1,
    const float* __restrict__ rnz0, const float* __restrict__ rnz1,
    const float* __restrict__ z, int zoff, int ld,
    float* __restrict__ outm, float* __restrict__ outs1, float* __restrict__ outs2,
    unsigned int* __restrict__ bitmap, float* __restrict__ lossacc)
{
    const int b = blockIdx.x, tid = threadIdx.x;
    const int lane = tid & 63, wv = tid >> 6;
    const int NC = NCHUNK * TOPK;   // 80

    __shared__ float zsh[DFULL];
    __shared__ float ssh[NCHUNK * TOPK];
    __shared__ float wk0[TOPK], wk1[TOPK];
    __shared__ int   ish[TOPK];
    __shared__ float serr[4];

    // stage z slice (original f32)
    const float* zrow = z + (size_t)b * DFULL + zoff;
    for (int c = tid; c < ld / 4; c += 256)
        ((float4*)zsh)[c] = ((const float4*)zrow)[c];
    __syncthreads();

    const float rz0 = rnz0[b];
    const float rz1 = w1 ? rnz1[b] : 0.f;
    const float* pvb = pv + (size_t)b * NC; (void)pvb;
    const int*   pib = pi + (size_t)b * NC;
    const float4* z4 = (const float4*)zsh;

    // exact f32 rescore of all candidates
    for (int c = wv; c < NC; c += 4) {
        int idx = pib[c];
        const float4* wr0 = (const float4*)(w0 + (size_t)idx * DHALF);
        float d0 = dot4(wr0[lane], z4[lane]) + dot4(wr0[64 + lane], z4[64 + lane]);
        float s = d0 * (rz0 * rn0[idx]);
        if (w1) {
            const float4* wr1 = (const float4*)(w1 + (size_t)idx * DHALF);
            float d1 = dot4(wr1[lane], z4[128 + lane]) + dot4(wr1[64 + lane], z4[192 + lane]);
            s += d1 * (rz1 * rn1[idx]);
        }
        #pragma unroll
        for (int off = 32; off; off >>= 1) s += __shfl_xor(s, off);
        if (lane == 0) ssh[c] = s;
    }
    __syncthreads();

    // wave 0: top-10 of 80 exact scores -> softmax -> weights*norm
    if (wv == 0) {
        float c0 = ssh[lane];
        float c1 = (lane < NC - 64) ? ssh[64 + lane] : -1e30f;
        float vk[TOPK]; int sk[TOPK];
        #pragma unroll
        for (int k = 0; k < TOPK; ++k) {
            float v = c0; int s = lane;
            if (c1 > v) { v = c1; s = 64 + lane; }
            #pragma unroll
            for (int off = 32; off; off >>= 1) {
                float ov = __shfl_xor(v, off);
                int   os = __shfl_xor(s, off);
                if (ov > v || (ov == v && os < s)) { v = ov; s = os; }
            }
            vk[k] = v; sk[k] = s;
            if (s < 64) { if (lane == s) c0 = -1e30f; }
            else        { if (lane == s - 64) c1 = -1e30f; }
        }
        if (lane == 0) {
            float vmax = vk[0], e[TOPK], sum = 0.f;
            #pragma unroll
            for (int k = 0; k < TOPK; ++k) { e[k] = expf(2.f * (vk[k] - vmax)); sum += e[k]; }
            #pragma unroll
            for (int k = 0; k < TOPK; ++k) {
                float w = e[k] / sum;
                int idx = pib[sk[k]];
                ish[k] = idx;
                wk0[k] = w * rn0[idx];
                wk1[k] = w1 ? (w * rn1[idx]) : 0.f;
                atomicOr(&bitmap[idx >> 5], 1u << (idx & 31));
            }
        }
    }
    __syncthreads();

    // mix from ORIGINAL f32 codebook rows (scaled by inv-norm), write out, loss
    float err = 0.f;
    const int ng = ld / 4;
    for (int g = tid; g < ng; g += 256) {
        int sec = (g >= 128) ? 1 : 0;        // only hit when ld==1024
        int gl  = g & 127;
        float4 a = {0.f, 0.f, 0.f, 0.f};
        if (sec == 0) {
            #pragma unroll
            for (int k = 0; k < TOPK; ++k) {
                float4 wv4 = ((const float4*)(w0 + (size_t)ish[k] * DHALF))[gl];
                a.x += wk0[k] * wv4.x; a.y += wk0[k] * wv4.y;
                a.z += wk0[k] * wv4.z; a.w += wk0[k] * wv4.w;
            }
        } else {
            #pragma unroll
            for (int k = 0; k < TOPK; ++k) {
                float4 wv4 = ((const float4*)(w1 + (size_t)ish[k] * DHALF))[gl];
                a.x += wk1[k] * wv4.x; a.y += wk1[k] * wv4.y;
                a.z += wk1[k] * wv4.z; a.w += wk1[k] * wv4.w;
            }
        }
        float4 zz = ((const float4*)zsh)[g];
        float dx = a.x - zz.x, dy = a.y - zz.y, dzv = a.z - zz.z, dw = a.w - zz.w;
        err += dx*dx + dy*dy + dzv*dzv + dw*dw;
        ((float4*)(outm + (size_t)b * ld))[g] = a;
        if (outs1) {
            if (sec == 0) ((float4*)(outs1 + (size_t)b * DHALF))[gl] = a;
            else          ((float4*)(outs2 + (size_t)b * DHALF))[gl] = a;
        }
    }
    #pragma unroll
    for (int off = 32; off; off >>= 1) err += __shfl_xor(err, off);
    if (lane == 0) serr[wv] = err;
    __syncthreads();
    if (tid == 0) atomicAdd(lossacc, serr[0] + serr[1] + serr[2] + serr[3]);
}

// ---------------- scalar outputs ----------------
__global__ __launch_bounds__(256) void k_scalars(const unsigned int* __restrict__ bm,
                                                 const float* __restrict__ lossacc,
                                                 float* __restrict__ out)
{
    __shared__ float red[4];
    int tid = threadIdx.x;
    float counts[3];
    for (int g = 0; g < 3; ++g) {
        unsigned c = 0;
        for (int w = tid; w < NE / 32; w += 256) c += __popc(bm[g * (NE / 32) + w]);
        float f = (float)c;
        #pragma unroll
        for (int off = 32; off; off >>= 1) f += __shfl_xor(f, off);
        if ((tid & 63) == 0) red[tid >> 6] = f;
        __syncthreads();
        counts[g] = red[0] + red[1] + red[2] + red[3];
        __syncthreads();
    }
    if (tid == 0) {
        float vq_s = lossacc[0] / (4096.f * 1024.f);
        float vq_t = lossacc[1] / (4096.f * 512.f);
        float vq_g = lossacc[2] / (4096.f * 512.f);
        out[0] = vq_s; out[1] = BETA_C * vq_s;
        out[2] = vq_t; out[3] = BETA_C * vq_t;
        out[4] = vq_g; out[5] = BETA_C * vq_g;
        out[6] = counts[0] / (float)NE;
        out[7] = counts[1] / (float)NE;
        out[8] = counts[2] / (float)NE;
    }
}

// ---------------- host launch ----------------
extern "C" void kernel_launch(void* const* d_in, const int* in_sizes, int n_in,
                              void* d_out, int out_size, void* d_ws, size_t ws_size,
                              hipStream_t stream) {
    const float* z    = (const float*)d_in[0];
    const float* w_t  = (const float*)d_in[1];
    const float* w_g  = (const float*)d_in[2];
    const float* w_st = (const float*)d_in[3];
    const float* w_sg = (const float*)d_in[4];
    float* out = (float*)d_out;

    uint8_t* ws = (uint8_t*)d_ws;
    const size_t OFF_ZN  = 0;                                          // bf16 [4096,1024]
    const size_t OFF_WSH = OFF_ZN  + (size_t)BATCH * DFULL * 2;        // bf16 [16384,1024]
    const size_t OFF_WT  = OFF_WSH + (size_t)NE * DFULL * 2;           // bf16 [16384,512]
    const size_t OFF_WG  = OFF_WT  + (size_t)NE * DHALF * 2;
    const size_t OFF_PV  = OFF_WG  + (size_t)NE * DHALF * 2;           // 3*4096*80 f32
    const size_t OFF_PI  = OFF_PV  + (size_t)3 * BATCH * NCHUNK * TOPK * 4;
    const size_t OFF_RN  = OFF_PI  + (size_t)3 * BATCH * NCHUNK * TOPK * 4;  // 4*16384 f32
    const size_t OFF_RNZ = OFF_RN  + (size_t)4 * NE * 4;               // 2*4096 f32
    const size_t OFF_BM  = OFF_RNZ + (size_t)2 * BATCH * 4;            // 3*2048 B
    const size_t OFF_LS  = OFF_BM  + (size_t)3 * (NE / 8);             // 3 f32 + pad

    uint16_t* zn   = (uint16_t*)(ws + OFF_ZN);
    uint16_t* wsh  = (uint16_t*)(ws + OFF_WSH);
    uint16_t* wt   = (uint16_t*)(ws + OFF_WT);
    uint16_t* wg   = (uint16_t*)(ws + OFF_WG);
    float*    pv   = (float*)(ws + OFF_PV);
    int*      pi   = (int*)(ws + OFF_PI);
    float*    rnst = (float*)(ws + OFF_RN);
    float*    rnsg = rnst + NE;
    float*    rnt  = rnsg + NE;
    float*    rng  = rnt + NE;
    float*    rnzt = (float*)(ws + OFF_RNZ);
    float*    rnzg = rnzt + BATCH;
    unsigned* bm   = (unsigned*)(ws + OFF_BM);
    float*    ls   = (float*)(ws + OFF_LS);

    hipMemsetAsync(ws + OFF_BM, 0, 3 * (NE / 8) + 64, stream);

    k_norm_z<<<BATCH, 256, 0, stream>>>(z, zn, rnzt, rnzg);
    k_norm_cb<<<NE, 128, 0, stream>>>(w_st, wsh,        DFULL, rnst);
    k_norm_cb<<<NE, 128, 0, stream>>>(w_sg, wsh + 512,  DFULL, rnsg);
    k_norm_cb<<<NE, 128, 0, stream>>>(w_t,  wt,         DHALF, rnt);
    k_norm_cb<<<NE, 128, 0, stream>>>(w_g,  wg,         DHALF, rng);

    const int PV1 = BATCH * NCHUNK * TOPK;  // 327680
    dim3 gg(BATCH / 64, NCHUNK);
    k_gemm_topk<<<gg, 256, 0, stream>>>(zn, DFULL, 0,   wsh, DFULL, DFULL, pv,           pi);
    k_gemm_topk<<<gg, 256, 0, stream>>>(zn, DFULL, 0,   wt,  DHALF, DHALF, pv + PV1,     pi + PV1);
    k_gemm_topk<<<gg, 256, 0, stream>>>(zn, DFULL, 512, wg,  DHALF, DHALF, pv + 2 * PV1, pi + 2 * PV1);

    const size_t O1 = (size_t)BATCH * DFULL;
    const size_t O2 = O1 + (size_t)BATCH * DHALF;
    const size_t O3 = O2 + (size_t)BATCH * DHALF;
    const size_t O4 = O3 + (size_t)BATCH * DHALF;
    const size_t O5 = O4 + (size_t)BATCH * DHALF;

    k_merge<<<BATCH, 256, 0, stream>>>(pv,           pi,           w_st, rnst, w_sg, rnsg,
                                       rnzt, rnzg, z, 0,   DFULL,
                                       out,      out + O1, out + O2, bm,              ls);
    k_merge<<<BATCH, 256, 0, stream>>>(pv + PV1,     pi + PV1,     w_t,  rnt,  nullptr, nullptr,
                                       rnzt, nullptr, z, 0,   DHALF,
                                       out + O3, nullptr,  nullptr,  bm + NE / 32,     ls + 1);
    k_merge<<<BATCH, 256, 0, stream>>>(pv + 2 * PV1, pi + 2 * PV1, w_g,  rng,  nullptr, nullptr,
                                       rnzg, nullptr, z, 512, DHALF,
                                       out + O4, nullptr,  nullptr,  bm + 2 * (NE / 32), ls + 2);

    k_scalars<<<1, 256, 0, stream>>>(bm, ls, out + O5);
}

// Round 3
// 2397.973 us; speedup vs baseline: 1.0805x; 1.0805x over previous
//
#include <hip/hip_runtime.h>
#include <stdint.h>

// ---------------- problem constants ----------------
#define NE      16384
#define BATCH   4096
#define DFULL   1024
#define DHALF   512
#define TOPK    10
#define NCHUNK  16
#define CHUNK   1024   // 16384 / 16
#define NCAND   (NCHUNK * 20)   // 320 packed candidates per row
#define MRES    24              // exact-rescore count
#define BETA_C  0.25f

typedef __bf16 bf16x8 __attribute__((ext_vector_type(8)));
typedef float  f32x4  __attribute__((ext_vector_type(4)));

__device__ inline uint16_t f2bf(float f) {
    unsigned u = __float_as_uint(f);
    unsigned r = (u + 0x7FFFu + ((u >> 16) & 1u)) >> 16;
    return (uint16_t)r;
}

// sortable pack: high 16 = order-preserving bf16-trunc of value, low 16 = idx
__device__ inline unsigned packcand(float v, int idx) {
    unsigned u = __float_as_uint(v);
    unsigned h = u >> 16;
    h = (u >> 31) ? (h ^ 0xFFFFu) : (h | 0x8000u);
    return (h << 16) | (unsigned)idx;
}

__device__ inline void gload16(const uint16_t* g, uint16_t* l) {
    __builtin_amdgcn_global_load_lds(
        (const __attribute__((address_space(1))) void*)(const void*)g,
        (__attribute__((address_space(3))) void*)l, 16, 0, 0);
}

__device__ inline float dot4(float4 a, float4 b) {
    return a.x*b.x + a.y*b.y + a.z*b.z + a.w*b.w;
}

// ---------------- normalization kernels ----------------
__global__ __launch_bounds__(256) void k_norm_z(const float* __restrict__ z,
                                                uint16_t* __restrict__ zn,
                                                float* __restrict__ rnzt,
                                                float* __restrict__ rnzg) {
    int b = blockIdx.x, t = threadIdx.x;
    const float4* zp = (const float4*)(z + (size_t)b * DFULL);
    float4 v = zp[t];
    float ss = v.x*v.x + v.y*v.y + v.z*v.z + v.w*v.w;
    #pragma unroll
    for (int off = 32; off; off >>= 1) ss += __shfl_xor(ss, off);
    __shared__ float red[4];
    if ((t & 63) == 0) red[t >> 6] = ss;
    __syncthreads();
    float tot = (t < 128) ? (red[0] + red[1]) : (red[2] + red[3]);
    float rn = rsqrtf(tot + 1e-12f);
    if (t == 0)   rnzt[b] = rn;
    if (t == 128) rnzg[b] = rn;
    uint16_t* o = zn + (size_t)b * DFULL + t * 4;
    o[0] = f2bf(v.x * rn); o[1] = f2bf(v.y * rn);
    o[2] = f2bf(v.z * rn); o[3] = f2bf(v.w * rn);
}

__global__ __launch_bounds__(128) void k_norm_cb(const float* __restrict__ w,
                                                 uint16_t* __restrict__ dst, int dstld,
                                                 float* __restrict__ rns) {
    int r = blockIdx.x, t = threadIdx.x;
    const float4* wp = (const float4*)(w + (size_t)r * DHALF);
    float4 v = wp[t];
    float ss = v.x*v.x + v.y*v.y + v.z*v.z + v.w*v.w;
    #pragma unroll
    for (int off = 32; off; off >>= 1) ss += __shfl_xor(ss, off);
    __shared__ float red[2];
    if ((t & 63) == 0) red[t >> 6] = ss;
    __syncthreads();
    float rn = rsqrtf(red[0] + red[1] + 1e-12f);
    if (t == 0) rns[r] = rn;
    uint16_t* o = dst + (size_t)r * dstld + t * 4;
    o[0] = f2bf(v.x * rn); o[1] = f2bf(v.y * rn);
    o[2] = f2bf(v.z * rn); o[3] = f2bf(v.w * rn);
}

// ---------------- fused 128x128 GEMM + per-row top-10 screen ----------------
// grid (32, 16); block 256 = 4 waves (2x2); wave (wr,wc) owns 64x64.
// 2-phase prefetch: STAGE(next) -> COMPUTE(cur) -> __syncthreads (vmcnt drain).
__global__ __launch_bounds__(256, 2) void k_gemm_topk(
    const uint16_t* __restrict__ An, int lda, int aoff,
    const uint16_t* __restrict__ Bn, int ldb, int KT,
    unsigned* __restrict__ cand)
{
    __shared__ uint16_t Asm[2][128 * 64];   // 2 x 16 KB, XOR-swizzled rows (128 B)
    __shared__ uint16_t Bsm[2][128 * 64];
    __shared__ unsigned top[4][64][TOPK];   // per-wave packed top-10 lists
    __shared__ unsigned thr[4][64];

    const int tid  = threadIdx.x;
    const int lane = tid & 63;
    const int wv   = tid >> 6;
    const int wr   = wv >> 1;
    const int wc   = wv & 1;
    const int rowbase = blockIdx.x * 128;
    const int colbase = blockIdx.y * CHUNK;

    for (int e = tid; e < 4 * 64 * TOPK; e += 256) ((unsigned*)top)[e] = 0u;
    ((unsigned*)thr)[tid] = 0u;
    __syncthreads();

    // staging: one K-step = A(128x64) + B(128x64) = 32 KB, 8 gload16/thread
    auto STAGE = [&](int cb2, int kt2, int bufi) {
        const uint16_t* Ag = An + (size_t)rowbase * lda + aoff + kt2 * 64;
        const uint16_t* Bg = Bn + (size_t)(colbase + cb2 * 128) * ldb + kt2 * 64;
        uint16_t* Ad = &Asm[bufi][0];
        uint16_t* Bd = &Bsm[bufi][0];
        #pragma unroll
        for (int it = 0; it < 4; ++it) {
            int q = it * 4 + wv;
            int o = q * 1024 + lane * 16;
            int row = o >> 7;
            int kb  = (o & 127) ^ ((row & 7) << 4);   // pre-swizzled source
            gload16(Ag + (size_t)row * lda + (kb >> 1), Ad + q * 512);
            gload16(Bg + (size_t)row * ldb + (kb >> 1), Bd + q * 512);
        }
    };

    int cur = 0;
    STAGE(0, 0, 0);
    __syncthreads();

    for (int cb = 0; cb < 8; ++cb) {
        f32x4 acc[4][4];
        #pragma unroll
        for (int m = 0; m < 4; ++m)
            #pragma unroll
            for (int n = 0; n < 4; ++n)
                acc[m][n] = (f32x4){0.f, 0.f, 0.f, 0.f};

        for (int kt = 0; kt < KT; ++kt) {
            int last = (kt + 1 == KT);
            int ncb = last ? cb + 1 : cb;
            int nkt = last ? 0 : kt + 1;
            if (ncb < 8) STAGE(ncb, nkt, cur ^ 1);

            const char* Ab = (const char*)&Asm[cur][0];
            const char* Bb = (const char*)&Bsm[cur][0];
            #pragma unroll
            for (int ks = 0; ks < 2; ++ks) {
                int kb = ks * 64 + ((lane >> 4) * 16);
                bf16x8 a[4], b[4];
                #pragma unroll
                for (int m = 0; m < 4; ++m) {
                    int ra = wr * 64 + m * 16 + (lane & 15);
                    a[m] = *(const bf16x8*)(Ab + ra * 128 + (kb ^ ((ra & 7) << 4)));
                }
                #pragma unroll
                for (int n = 0; n < 4; ++n) {
                    int rb = wc * 64 + n * 16 + (lane & 15);
                    b[n] = *(const bf16x8*)(Bb + rb * 128 + (kb ^ ((rb & 7) << 4)));
                }
                #pragma unroll
                for (int m = 0; m < 4; ++m)
                    #pragma unroll
                    for (int n = 0; n < 4; ++n)
                        acc[m][n] = __builtin_amdgcn_mfma_f32_16x16x32_bf16(
                                        a[m], b[n], acc[m][n], 0, 0, 0);
            }
            __syncthreads();   // vmcnt(0) drain waits for the PREFETCH (hidden under compute)
            cur ^= 1;
        }

        // ---- top-k screen update (per-wave lists; 4-way row-parallel insert) ----
        #pragma unroll
        for (int m = 0; m < 4; ++m) {
            #pragma unroll
            for (int i = 0; i < 4; ++i) {
                int rbase = m * 16 + (lane >> 4) * 4 + i;
                #pragma unroll
                for (int n = 0; n < 4; ++n) {
                    int col = colbase + cb * 128 + wc * 64 + n * 16 + (lane & 15);
                    unsigned pc = packcand(acc[m][n][i], col);
                    unsigned thrv = thr[wv][rbase];
                    unsigned long long msk = __ballot(pc > thrv);
                    if (!msk) continue;
                    unsigned sub = (unsigned)((msk >> (lane & 48)) & 0xFFFFull);
                    bool ins = (lane & 15) == 0;
                    for (;;) {
                        bool act = ins && (sub != 0u);
                        if (!__any(act)) break;
                        int srcrel = sub ? (__ffs(sub) - 1) : 0;
                        unsigned cv = __shfl(pc, (lane & 48) + srcrel);
                        if (act) {
                            sub &= sub - 1u;
                            unsigned mn = 0xFFFFFFFFu, mn2 = 0xFFFFFFFFu; int mp = 0;
                            #pragma unroll
                            for (int j = 0; j < TOPK; ++j) {
                                unsigned x = top[wv][rbase][j];
                                if (x < mn) { mn2 = mn; mn = x; mp = j; }
                                else if (x < mn2) mn2 = x;
                            }
                            if (cv > mn) {
                                top[wv][rbase][mp] = cv;
                                thr[wv][rbase] = (mn2 < cv) ? mn2 : cv;
                            }
                        }
                    }
                }
            }
        }
    }

    // write packed candidates: cand[row][chunk][wc][10]
    for (int e = lane; e < 64 * TOPK; e += 64) {
        int r = e / TOPK, j = e % TOPK;
        int grow = rowbase + wr * 64 + r;
        cand[(size_t)grow * NCAND + blockIdx.y * 20 + wc * TOPK + j] = top[wv][r][j];
    }
}

// ---------------- screen top-24 + exact rescore + softmax + mix + losses ----------------
__global__ __launch_bounds__(256) void k_merge(
    const unsigned* __restrict__ cand,
    const float* __restrict__ w0, const float* __restrict__ rn0,
    const float* __restrict__ w1, const float* __restrict__ rn1,
    const float* __restrict__ rnz0, const float* __restrict__ rnz1,
    const float* __restrict__ z, int zoff, int ld,
    float* __restrict__ outm, float* __restrict__ outs1, float* __restrict__ outs2,
    unsigned int* __restrict__ bitmap, float* __restrict__ lossacc)
{
    const int b = blockIdx.x, tid = threadIdx.x;
    const int lane = tid & 63, wv = tid >> 6;

    __shared__ float zsh[DFULL];
    __shared__ unsigned scand[MRES];
    __shared__ float ssh[MRES];
    __shared__ float wk0[TOPK], wk1[TOPK];
    __shared__ int   ish[TOPK];
    __shared__ float serr[4];

    const float* zrow = z + (size_t)b * DFULL + zoff;
    for (int c = tid; c < ld / 4; c += 256)
        ((float4*)zsh)[c] = ((const float4*)zrow)[c];

    // wave 0: top-24 of 320 packed candidates by value
    if (wv == 0) {
        unsigned c[5];
        const unsigned* cb_ = cand + (size_t)b * NCAND;
        #pragma unroll
        for (int j = 0; j < 5; ++j) c[j] = cb_[lane + 64 * j];
        for (int k = 0; k < MRES; ++k) {
            unsigned bv = 0; int bj = 0;
            #pragma unroll
            for (int j = 0; j < 5; ++j) if (c[j] > bv) { bv = c[j]; bj = j; }
            unsigned v = bv; int who = lane;
            #pragma unroll
            for (int off = 32; off; off >>= 1) {
                unsigned ov = __shfl_xor(v, off);
                int      ow = __shfl_xor(who, off);
                if (ov > v) { v = ov; who = ow; }
            }
            if (lane == who) c[bj] = 0u;
            if (lane == 0) scand[k] = v;
        }
    }
    __syncthreads();

    // exact f32 rescore of the 24 survivors
    const float rz0 = rnz0[b];
    const float rz1 = w1 ? rnz1[b] : 0.f;
    const float4* z4 = (const float4*)zsh;
    for (int cc = wv; cc < MRES; cc += 4) {
        int idx = scand[cc] & 0xFFFFu;
        const float4* wr0 = (const float4*)(w0 + (size_t)idx * DHALF);
        float d0 = dot4(wr0[lane], z4[lane]) + dot4(wr0[64 + lane], z4[64 + lane]);
        float s = d0 * (rz0 * rn0[idx]);
        if (w1) {
            const float4* wr1 = (const float4*)(w1 + (size_t)idx * DHALF);
            float d1 = dot4(wr1[lane], z4[128 + lane]) + dot4(wr1[64 + lane], z4[192 + lane]);
            s += d1 * (rz1 * rn1[idx]);
        }
        #pragma unroll
        for (int off = 32; off; off >>= 1) s += __shfl_xor(s, off);
        if (lane == 0) ssh[cc] = s;
    }
    __syncthreads();

    // wave 0: exact top-10 of 24 -> softmax weights
    if (wv == 0) {
        float val = (lane < MRES) ? ssh[lane] : -1e30f;
        float vk[TOPK]; int sk[TOPK];
        #pragma unroll
        for (int k = 0; k < TOPK; ++k) {
            float v = val; int who = lane;
            #pragma unroll
            for (int off = 32; off; off >>= 1) {
                float ov = __shfl_xor(v, off);
                int   ow = __shfl_xor(who, off);
                if (ov > v || (ov == v && ow < who)) { v = ov; who = ow; }
            }
            vk[k] = v; sk[k] = who;
            if (lane == who) val = -1e30f;
        }
        if (lane == 0) {
            float vmax = vk[0], e[TOPK], sum = 0.f;
            #pragma unroll
            for (int k = 0; k < TOPK; ++k) { e[k] = expf(2.f * (vk[k] - vmax)); sum += e[k]; }
            #pragma unroll
            for (int k = 0; k < TOPK; ++k) {
                float w = e[k] / sum;
                int idx = scand[sk[k]] & 0xFFFFu;
                ish[k] = idx;
                wk0[k] = w * rn0[idx];
                wk1[k] = w1 ? (w * rn1[idx]) : 0.f;
                atomicOr(&bitmap[idx >> 5], 1u << (idx & 31));
            }
        }
    }
    __syncthreads();

    // mix from ORIGINAL f32 codebook rows, write outputs, loss
    float err = 0.f;
    const int ng = ld / 4;
    for (int g = tid; g < ng; g += 256) {
        int sec = (g >= 128) ? 1 : 0;
        int gl  = g & 127;
        float4 a = {0.f, 0.f, 0.f, 0.f};
        if (sec == 0) {
            #pragma unroll
            for (int k = 0; k < TOPK; ++k) {
                float4 wv4 = ((const float4*)(w0 + (size_t)ish[k] * DHALF))[gl];
                a.x += wk0[k] * wv4.x; a.y += wk0[k] * wv4.y;
                a.z += wk0[k] * wv4.z; a.w += wk0[k] * wv4.w;
            }
        } else {
            #pragma unroll
            for (int k = 0; k < TOPK; ++k) {
                float4 wv4 = ((const float4*)(w1 + (size_t)ish[k] * DHALF))[gl];
                a.x += wk1[k] * wv4.x; a.y += wk1[k] * wv4.y;
                a.z += wk1[k] * wv4.z; a.w += wk1[k] * wv4.w;
            }
        }
        float4 zz = ((const float4*)zsh)[g];
        float dx = a.x - zz.x, dy = a.y - zz.y, dzv = a.z - zz.z, dw = a.w - zz.w;
        err += dx*dx + dy*dy + dzv*dzv + dw*dw;
        ((float4*)(outm + (size_t)b * ld))[g] = a;
        if (outs1) {
            if (sec == 0) ((float4*)(outs1 + (size_t)b * DHALF))[gl] = a;
            else          ((float4*)(outs2 + (size_t)b * DHALF))[gl] = a;
        }
    }
    #pragma unroll
    for (int off = 32; off; off >>= 1) err += __shfl_xor(err, off);
    if (lane == 0) serr[wv] = err;
    __syncthreads();
    if (tid == 0) atomicAdd(lossacc, serr[0] + serr[1] + serr[2] + serr[3]);
}

// ---------------- scalar outputs ----------------
__global__ __launch_bounds__(256) void k_scalars(const unsigned int* __restrict__ bm,
                                                 const float* __restrict__ lossacc,
                                                 float* __restrict__ out)
{
    __shared__ float red[4];
    int tid = threadIdx.x;
    float counts[3];
    for (int g = 0; g < 3; ++g) {
        unsigned c = 0;
        for (int w = tid; w < NE / 32; w += 256) c += __popc(bm[g * (NE / 32) + w]);
        float f = (float)c;
        #pragma unroll
        for (int off = 32; off; off >>= 1) f += __shfl_xor(f, off);
        if ((tid & 63) == 0) red[tid >> 6] = f;
        __syncthreads();
        counts[g] = red[0] + red[1] + red[2] + red[3];
        __syncthreads();
    }
    if (tid == 0) {
        float vq_s = lossacc[0] / (4096.f * 1024.f);
        float vq_t = lossacc[1] / (4096.f * 512.f);
        float vq_g = lossacc[2] / (4096.f * 512.f);
        out[0] = vq_s; out[1] = BETA_C * vq_s;
        out[2] = vq_t; out[3] = BETA_C * vq_t;
        out[4] = vq_g; out[5] = BETA_C * vq_g;
        out[6] = counts[0] / (float)NE;
        out[7] = counts[1] / (float)NE;
        out[8] = counts[2] / (float)NE;
    }
}

// ---------------- host launch ----------------
extern "C" void kernel_launch(void* const* d_in, const int* in_sizes, int n_in,
                              void* d_out, int out_size, void* d_ws, size_t ws_size,
                              hipStream_t stream) {
    const float* z    = (const float*)d_in[0];
    const float* w_t  = (const float*)d_in[1];
    const float* w_g  = (const float*)d_in[2];
    const float* w_st = (const float*)d_in[3];
    const float* w_sg = (const float*)d_in[4];
    float* out = (float*)d_out;

    uint8_t* ws = (uint8_t*)d_ws;
    const size_t OFF_ZN  = 0;                                          // bf16 [4096,1024]
    const size_t OFF_WSH = OFF_ZN  + (size_t)BATCH * DFULL * 2;        // bf16 [16384,1024]
    const size_t OFF_WT  = OFF_WSH + (size_t)NE * DFULL * 2;           // bf16 [16384,512]
    const size_t OFF_WG  = OFF_WT  + (size_t)NE * DHALF * 2;
    const size_t OFF_CD  = OFF_WG  + (size_t)NE * DHALF * 2;           // 3*4096*320 u32
    const size_t OFF_RN  = OFF_CD  + (size_t)3 * BATCH * NCAND * 4;
    const size_t OFF_RNZ = OFF_RN  + (size_t)4 * NE * 4;
    const size_t OFF_BM  = OFF_RNZ + (size_t)2 * BATCH * 4;
    const size_t OFF_LS  = OFF_BM  + (size_t)3 * (NE / 8);

    uint16_t* zn   = (uint16_t*)(ws + OFF_ZN);
    uint16_t* wsh  = (uint16_t*)(ws + OFF_WSH);
    uint16_t* wt   = (uint16_t*)(ws + OFF_WT);
    uint16_t* wg   = (uint16_t*)(ws + OFF_WG);
    unsigned* cd   = (unsigned*)(ws + OFF_CD);
    float*    rnst = (float*)(ws + OFF_RN);
    float*    rnsg = rnst + NE;
    float*    rnt  = rnsg + NE;
    float*    rng  = rnt + NE;
    float*    rnzt = (float*)(ws + OFF_RNZ);
    float*    rnzg = rnzt + BATCH;
    unsigned* bm   = (unsigned*)(ws + OFF_BM);
    float*    ls   = (float*)(ws + OFF_LS);

    hipMemsetAsync(ws + OFF_BM, 0, 3 * (NE / 8) + 64, stream);

    k_norm_z<<<BATCH, 256, 0, stream>>>(z, zn, rnzt, rnzg);
    k_norm_cb<<<NE, 128, 0, stream>>>(w_st, wsh,        DFULL, rnst);
    k_norm_cb<<<NE, 128, 0, stream>>>(w_sg, wsh + 512,  DFULL, rnsg);
    k_norm_cb<<<NE, 128, 0, stream>>>(w_t,  wt,         DHALF, rnt);
    k_norm_cb<<<NE, 128, 0, stream>>>(w_g,  wg,         DHALF, rng);

    const size_t CD1 = (size_t)BATCH * NCAND;
    dim3 gg(BATCH / 128, NCHUNK);
    k_gemm_topk<<<gg, 256, 0, stream>>>(zn, DFULL, 0,   wsh, DFULL, 16, cd);
    k_gemm_topk<<<gg, 256, 0, stream>>>(zn, DFULL, 0,   wt,  DHALF,  8, cd + CD1);
    k_gemm_topk<<<gg, 256, 0, stream>>>(zn, DFULL, 512, wg,  DHALF,  8, cd + 2 * CD1);

    const size_t O1 = (size_t)BATCH * DFULL;
    const size_t O2 = O1 + (size_t)BATCH * DHALF;
    const size_t O3 = O2 + (size_t)BATCH * DHALF;
    const size_t O4 = O3 + (size_t)BATCH * DHALF;
    const size_t O5 = O4 + (size_t)BATCH * DHALF;

    k_merge<<<BATCH, 256, 0, stream>>>(cd,           w_st, rnst, w_sg, rnsg,
                                       rnzt, rnzg, z, 0,   DFULL,
                                       out,      out + O1, out + O2, bm,               ls);
    k_merge<<<BATCH, 256, 0, stream>>>(cd + CD1,     w_t,  rnt,  nullptr, nullptr,
                                       rnzt, nullptr, z, 0,   DHALF,
                                       out + O3, nullptr,  nullptr,  bm + NE / 32,     ls + 1);
    k_merge<<<BATCH, 256, 0, stream>>>(cd + 2 * CD1, w_g,  rng,  nullptr, nullptr,
                                       rnzg, nullptr, z, 512, DHALF,
                                       out + O4, nullptr,  nullptr,  bm + 2 * (NE / 32), ls + 2);

    k_scalars<<<1, 256, 0, stream>>>(bm, ls, out + O5);
}

// Round 4
// 1592.860 us; speedup vs baseline: 1.6266x; 1.5055x over previous
//
#include <hip/hip_runtime.h>
#include <stdint.h>

// ---------------- problem constants ----------------
#define NE      16384
#define BATCH   4096
#define DFULL   1024
#define DHALF   512
#define TOPK    10
#define NCHUNK  16
#define CHUNK   1024            // entries per chunk (16384 / 16)
#define LPER    5               // per-lane list depth
#define CPC     40              // candidates per row per chunk (2 wr * 4 q * 5)
#define NCAND   (NCHUNK * CPC)  // 640 candidates per row
#define MRES    24              // exact-rescore count
#define BETA_C  0.25f

typedef __bf16 bf16x8 __attribute__((ext_vector_type(8)));
typedef float  f32x4  __attribute__((ext_vector_type(4)));

__device__ inline uint16_t f2bf(float f) {
    unsigned u = __float_as_uint(f);
    unsigned r = (u + 0x7FFFu + ((u >> 16) & 1u)) >> 16;
    return (uint16_t)r;
}

__device__ inline void gload16(const uint16_t* g, uint16_t* l) {
    __builtin_amdgcn_global_load_lds(
        (const __attribute__((address_space(1))) void*)(const void*)g,
        (__attribute__((address_space(3))) void*)l, 16, 0, 0);
}

__device__ inline float dot4(float4 a, float4 b) {
    return a.x*b.x + a.y*b.y + a.z*b.z + a.w*b.w;
}

// ---------------- normalization kernels ----------------
__global__ __launch_bounds__(256) void k_norm_z(const float* __restrict__ z,
                                                uint16_t* __restrict__ zn,
                                                float* __restrict__ rnzt,
                                                float* __restrict__ rnzg) {
    int b = blockIdx.x, t = threadIdx.x;
    const float4* zp = (const float4*)(z + (size_t)b * DFULL);
    float4 v = zp[t];
    float ss = v.x*v.x + v.y*v.y + v.z*v.z + v.w*v.w;
    #pragma unroll
    for (int off = 32; off; off >>= 1) ss += __shfl_xor(ss, off);
    __shared__ float red[4];
    if ((t & 63) == 0) red[t >> 6] = ss;
    __syncthreads();
    float tot = (t < 128) ? (red[0] + red[1]) : (red[2] + red[3]);
    float rn = rsqrtf(tot + 1e-12f);
    if (t == 0)   rnzt[b] = rn;
    if (t == 128) rnzg[b] = rn;
    uint16_t* o = zn + (size_t)b * DFULL + t * 4;
    o[0] = f2bf(v.x * rn); o[1] = f2bf(v.y * rn);
    o[2] = f2bf(v.z * rn); o[3] = f2bf(v.w * rn);
}

__global__ __launch_bounds__(128) void k_norm_cb(const float* __restrict__ w,
                                                 uint16_t* __restrict__ dst, int dstld,
                                                 float* __restrict__ rns) {
    int r = blockIdx.x, t = threadIdx.x;
    const float4* wp = (const float4*)(w + (size_t)r * DHALF);
    float4 v = wp[t];
    float ss = v.x*v.x + v.y*v.y + v.z*v.z + v.w*v.w;
    #pragma unroll
    for (int off = 32; off; off >>= 1) ss += __shfl_xor(ss, off);
    __shared__ float red[2];
    if ((t & 63) == 0) red[t >> 6] = ss;
    __syncthreads();
    float rn = rsqrtf(red[0] + red[1] + 1e-12f);
    if (t == 0) rns[r] = rn;
    uint16_t* o = dst + (size_t)r * dstld + t * 4;
    o[0] = f2bf(v.x * rn); o[1] = f2bf(v.y * rn);
    o[2] = f2bf(v.z * rn); o[3] = f2bf(v.w * rn);
}

// ---------------- fused 128x128 GEMM (S^T) + per-lane register top-5 screen ----
// C rows = codebook entries, C cols = batch rows. grid (BATCH/128, NCHUNK).
// block 256 = 4 waves 2x2; wave (wr=entry-half, wc=batch-half).
// Each lane keeps 4 sorted top-5 lists (one per owned batch row) in VGPRs.
__global__ __launch_bounds__(256, 2) void k_gemm_topk(
    const uint16_t* __restrict__ Zn, int ldz, int zoff,
    const uint16_t* __restrict__ Wn, int ldw, int KT,
    unsigned* __restrict__ cand)
{
    __shared__ uint16_t Wsm[2][128 * 64];   // entries x k, XOR-swizzled 128B rows
    __shared__ uint16_t Zsm[2][128 * 64];   // batch   x k

    const int tid  = threadIdx.x;
    const int lane = tid & 63;
    const int wv   = tid >> 6;
    const int wr   = wv >> 1;
    const int wc   = wv & 1;
    const int q    = lane >> 4;
    const int c    = lane & 15;
    const int rowbase  = blockIdx.x * 128;     // batch rows
    const int entchunk = blockIdx.y * CHUNK;   // entry base

    auto STAGE = [&](int cb2, int kt2, int bufi) {
        const uint16_t* Wg = Wn + (size_t)(entchunk + cb2 * 128) * ldw + kt2 * 64;
        const uint16_t* Zg = Zn + (size_t)rowbase * ldz + zoff + kt2 * 64;
        uint16_t* Wd = &Wsm[bufi][0];
        uint16_t* Zd = &Zsm[bufi][0];
        #pragma unroll
        for (int it = 0; it < 4; ++it) {
            int qq = it * 4 + wv;
            int o = qq * 1024 + lane * 16;
            int row = o >> 7;
            int kb  = (o & 127) ^ ((row & 7) << 4);   // pre-swizzled source (m173)
            gload16(Wg + (size_t)row * ldw + (kb >> 1), Wd + qq * 512);
            gload16(Zg + (size_t)row * ldz + (kb >> 1), Zd + qq * 512);
        }
    };

    // per-lane sorted lists (descending), packed (sortable16(v)<<16)|entry_idx
    unsigned L0[4] = {0,0,0,0}, L1[4] = {0,0,0,0}, L2[4] = {0,0,0,0},
             L3[4] = {0,0,0,0}, L4[4] = {0,0,0,0};

    STAGE(0, 0, 0);
    __syncthreads();
    int cur = 0;

    for (int cb = 0; cb < 8; ++cb) {
        f32x4 acc[4][4];
        #pragma unroll
        for (int m = 0; m < 4; ++m)
            #pragma unroll
            for (int n = 0; n < 4; ++n)
                acc[m][n] = (f32x4){0.f, 0.f, 0.f, 0.f};

        for (int kt = 0; kt < KT; ++kt) {
            int last = (kt + 1 == KT);
            int ncb = last ? cb + 1 : cb;
            int nkt = last ? 0 : kt + 1;
            if (ncb < 8) STAGE(ncb, nkt, cur ^ 1);

            const char* Wb = (const char*)&Wsm[cur][0];
            const char* Zb = (const char*)&Zsm[cur][0];
            #pragma unroll
            for (int ks = 0; ks < 2; ++ks) {
                int kb = ks * 64 + q * 16;
                bf16x8 a[4], b[4];
                #pragma unroll
                for (int m = 0; m < 4; ++m) {
                    int ra = wr * 64 + m * 16 + c;
                    a[m] = *(const bf16x8*)(Wb + ra * 128 + (kb ^ ((ra & 7) << 4)));
                }
                #pragma unroll
                for (int n = 0; n < 4; ++n) {
                    int rb = wc * 64 + n * 16 + c;
                    b[n] = *(const bf16x8*)(Zb + rb * 128 + (kb ^ ((rb & 7) << 4)));
                }
                #pragma unroll
                for (int m = 0; m < 4; ++m)
                    #pragma unroll
                    for (int n = 0; n < 4; ++n)
                        acc[m][n] = __builtin_amdgcn_mfma_f32_16x16x32_bf16(
                                        a[m], b[n], acc[m][n], 0, 0, 0);
            }
            __syncthreads();   // also drains the prefetch vmcnt (hidden under MFMA)
            cur ^= 1;
        }

        // ---- per-lane branchless top-5 screen (no cross-lane ops) ----
        const int entbase = entchunk + cb * 128 + wr * 64 + q * 4;
        #pragma unroll
        for (int n = 0; n < 4; ++n) {
            #pragma unroll
            for (int m = 0; m < 4; ++m) {
                #pragma unroll
                for (int i = 0; i < 4; ++i) {
                    unsigned u  = __float_as_uint(acc[m][n][i]);
                    unsigned mg = (unsigned)((int)u >> 31);
                    unsigned h  = (u >> 16) ^ (mg | 0x8000u);
                    unsigned p  = (h << 16) | (unsigned)(entbase + m * 16 + i);
                    bool g0 = p > L0[n], g1 = p > L1[n], g2 = p > L2[n],
                         g3 = p > L3[n], g4 = p > L4[n];
                    L4[n] = g4 ? (g3 ? L3[n] : p) : L4[n];
                    L3[n] = g3 ? (g2 ? L2[n] : p) : L3[n];
                    L2[n] = g2 ? (g1 ? L1[n] : p) : L2[n];
                    L1[n] = g1 ? (g0 ? L0[n] : p) : L1[n];
                    L0[n] = g0 ? p : L0[n];
                }
            }
        }
    }

    // write per-lane lists: cand[row][chunk][wr][q][5]
    #pragma unroll
    for (int n = 0; n < 4; ++n) {
        int grow = rowbase + wc * 64 + n * 16 + c;
        unsigned* dst = cand + ((size_t)grow * NCHUNK + blockIdx.y) * CPC + wr * 20 + q * 5;
        dst[0] = L0[n]; dst[1] = L1[n]; dst[2] = L2[n]; dst[3] = L3[n]; dst[4] = L4[n];
    }
}

// ---------------- screen top-24 + exact rescore + softmax + mix + losses ----------------
__global__ __launch_bounds__(256) void k_merge(
    const unsigned* __restrict__ cand,
    const float* __restrict__ w0, const float* __restrict__ rn0,
    const float* __restrict__ w1, const float* __restrict__ rn1,
    const float* __restrict__ rnz0, const float* __restrict__ rnz1,
    const float* __restrict__ z, int zoff, int ld,
    float* __restrict__ outm, float* __restrict__ outs1, float* __restrict__ outs2,
    unsigned int* __restrict__ bitmap, float* __restrict__ lossacc)
{
    const int b = blockIdx.x, tid = threadIdx.x;
    const int lane = tid & 63, wv = tid >> 6;

    __shared__ float zsh[DFULL];
    __shared__ unsigned scand[MRES];
    __shared__ float ssh[MRES];
    __shared__ float wk0[TOPK], wk1[TOPK];
    __shared__ int   ish[TOPK];
    __shared__ float serr[4];

    const float* zrow = z + (size_t)b * DFULL + zoff;
    for (int cc = tid; cc < ld / 4; cc += 256)
        ((float4*)zsh)[cc] = ((const float4*)zrow)[cc];

    // wave 0: top-24 of 640 packed candidates (value-clear extraction, no runtime idx)
    if (wv == 0) {
        unsigned creg[10];
        const unsigned* cb_ = cand + (size_t)b * NCAND;
        #pragma unroll
        for (int j = 0; j < 10; ++j) creg[j] = cb_[lane + 64 * j];
        for (int k = 0; k < MRES; ++k) {
            unsigned bv = 0;
            #pragma unroll
            for (int j = 0; j < 10; ++j) bv = (creg[j] > bv) ? creg[j] : bv;
            #pragma unroll
            for (int off = 32; off; off >>= 1) {
                unsigned ov = __shfl_xor(bv, off);
                bv = (ov > bv) ? ov : bv;
            }
            #pragma unroll
            for (int j = 0; j < 10; ++j) if (creg[j] == bv) creg[j] = 0u;
            if (lane == 0) scand[k] = bv;
        }
    }
    __syncthreads();

    // exact f32 rescore of the 24 survivors
    const float rz0 = rnz0[b];
    const float rz1 = w1 ? rnz1[b] : 0.f;
    const float4* z4 = (const float4*)zsh;
    for (int cc = wv; cc < MRES; cc += 4) {
        int idx = scand[cc] & 0xFFFFu;
        const float4* wr0 = (const float4*)(w0 + (size_t)idx * DHALF);
        float d0 = dot4(wr0[lane], z4[lane]) + dot4(wr0[64 + lane], z4[64 + lane]);
        float s = d0 * (rz0 * rn0[idx]);
        if (w1) {
            const float4* wr1 = (const float4*)(w1 + (size_t)idx * DHALF);
            float d1 = dot4(wr1[lane], z4[128 + lane]) + dot4(wr1[64 + lane], z4[192 + lane]);
            s += d1 * (rz1 * rn1[idx]);
        }
        #pragma unroll
        for (int off = 32; off; off >>= 1) s += __shfl_xor(s, off);
        if (lane == 0) ssh[cc] = s;
    }
    __syncthreads();

    // wave 0: exact top-10 of 24 -> softmax weights
    if (wv == 0) {
        float val = (lane < MRES) ? ssh[lane] : -1e30f;
        float vk[TOPK]; int sk[TOPK];
        #pragma unroll
        for (int k = 0; k < TOPK; ++k) {
            float v = val; int who = lane;
            #pragma unroll
            for (int off = 32; off; off >>= 1) {
                float ov = __shfl_xor(v, off);
                int   ow = __shfl_xor(who, off);
                if (ov > v || (ov == v && ow < who)) { v = ov; who = ow; }
            }
            vk[k] = v; sk[k] = who;
            if (lane == who) val = -1e30f;
        }
        if (lane == 0) {
            float vmax = vk[0], e[TOPK], sum = 0.f;
            #pragma unroll
            for (int k = 0; k < TOPK; ++k) { e[k] = expf(2.f * (vk[k] - vmax)); sum += e[k]; }
            #pragma unroll
            for (int k = 0; k < TOPK; ++k) {
                float w = e[k] / sum;
                int idx = scand[sk[k]] & 0xFFFFu;
                ish[k] = idx;
                wk0[k] = w * rn0[idx];
                wk1[k] = w1 ? (w * rn1[idx]) : 0.f;
                atomicOr(&bitmap[idx >> 5], 1u << (idx & 31));
            }
        }
    }
    __syncthreads();

    // mix from ORIGINAL f32 codebook rows, write outputs, loss
    float err = 0.f;
    const int ng = ld / 4;
    for (int g = tid; g < ng; g += 256) {
        int sec = (g >= 128) ? 1 : 0;
        int gl  = g & 127;
        float4 a = {0.f, 0.f, 0.f, 0.f};
        if (sec == 0) {
            #pragma unroll
            for (int k = 0; k < TOPK; ++k) {
                float4 wv4 = ((const float4*)(w0 + (size_t)ish[k] * DHALF))[gl];
                a.x += wk0[k] * wv4.x; a.y += wk0[k] * wv4.y;
                a.z += wk0[k] * wv4.z; a.w += wk0[k] * wv4.w;
            }
        } else {
            #pragma unroll
            for (int k = 0; k < TOPK; ++k) {
                float4 wv4 = ((const float4*)(w1 + (size_t)ish[k] * DHALF))[gl];
                a.x += wk1[k] * wv4.x; a.y += wk1[k] * wv4.y;
                a.z += wk1[k] * wv4.z; a.w += wk1[k] * wv4.w;
            }
        }
        float4 zz = ((const float4*)zsh)[g];
        float dx = a.x - zz.x, dy = a.y - zz.y, dzv = a.z - zz.z, dw = a.w - zz.w;
        err += dx*dx + dy*dy + dzv*dzv + dw*dw;
        ((float4*)(outm + (size_t)b * ld))[g] = a;
        if (outs1) {
            if (sec == 0) ((float4*)(outs1 + (size_t)b * DHALF))[gl] = a;
            else          ((float4*)(outs2 + (size_t)b * DHALF))[gl] = a;
        }
    }
    #pragma unroll
    for (int off = 32; off; off >>= 1) err += __shfl_xor(err, off);
    if (lane == 0) serr[wv] = err;
    __syncthreads();
    if (tid == 0) atomicAdd(lossacc, serr[0] + serr[1] + serr[2] + serr[3]);
}

// ---------------- scalar outputs ----------------
__global__ __launch_bounds__(256) void k_scalars(const unsigned int* __restrict__ bm,
                                                 const float* __restrict__ lossacc,
                                                 float* __restrict__ out)
{
    __shared__ float red[4];
    int tid = threadIdx.x;
    float counts[3];
    for (int g = 0; g < 3; ++g) {
        unsigned c = 0;
        for (int w = tid; w < NE / 32; w += 256) c += __popc(bm[g * (NE / 32) + w]);
        float f = (float)c;
        #pragma unroll
        for (int off = 32; off; off >>= 1) f += __shfl_xor(f, off);
        if ((tid & 63) == 0) red[tid >> 6] = f;
        __syncthreads();
        counts[g] = red[0] + red[1] + red[2] + red[3];
        __syncthreads();
    }
    if (tid == 0) {
        float vq_s = lossacc[0] / (4096.f * 1024.f);
        float vq_t = lossacc[1] / (4096.f * 512.f);
        float vq_g = lossacc[2] / (4096.f * 512.f);
        out[0] = vq_s; out[1] = BETA_C * vq_s;
        out[2] = vq_t; out[3] = BETA_C * vq_t;
        out[4] = vq_g; out[5] = BETA_C * vq_g;
        out[6] = counts[0] / (float)NE;
        out[7] = counts[1] / (float)NE;
        out[8] = counts[2] / (float)NE;
    }
}

// ---------------- host launch ----------------
extern "C" void kernel_launch(void* const* d_in, const int* in_sizes, int n_in,
                              void* d_out, int out_size, void* d_ws, size_t ws_size,
                              hipStream_t stream) {
    const float* z    = (const float*)d_in[0];
    const float* w_t  = (const float*)d_in[1];
    const float* w_g  = (const float*)d_in[2];
    const float* w_st = (const float*)d_in[3];
    const float* w_sg = (const float*)d_in[4];
    float* out = (float*)d_out;

    uint8_t* ws = (uint8_t*)d_ws;
    const size_t OFF_ZN  = 0;                                          // bf16 [4096,1024]
    const size_t OFF_WSH = OFF_ZN  + (size_t)BATCH * DFULL * 2;        // bf16 [16384,1024]
    const size_t OFF_WT  = OFF_WSH + (size_t)NE * DFULL * 2;           // bf16 [16384,512]
    const size_t OFF_WG  = OFF_WT  + (size_t)NE * DHALF * 2;
    const size_t OFF_CD  = OFF_WG  + (size_t)NE * DHALF * 2;           // 3*4096*640 u32
    const size_t OFF_RN  = OFF_CD  + (size_t)3 * BATCH * NCAND * 4;
    const size_t OFF_RNZ = OFF_RN  + (size_t)4 * NE * 4;
    const size_t OFF_BM  = OFF_RNZ + (size_t)2 * BATCH * 4;
    const size_t OFF_LS  = OFF_BM  + (size_t)3 * (NE / 8);

    uint16_t* zn   = (uint16_t*)(ws + OFF_ZN);
    uint16_t* wsh  = (uint16_t*)(ws + OFF_WSH);
    uint16_t* wt   = (uint16_t*)(ws + OFF_WT);
    uint16_t* wg   = (uint16_t*)(ws + OFF_WG);
    unsigned* cd   = (unsigned*)(ws + OFF_CD);
    float*    rnst = (float*)(ws + OFF_RN);
    float*    rnsg = rnst + NE;
    float*    rnt  = rnsg + NE;
    float*    rng  = rnt + NE;
    float*    rnzt = (float*)(ws + OFF_RNZ);
    float*    rnzg = rnzt + BATCH;
    unsigned* bm   = (unsigned*)(ws + OFF_BM);
    float*    ls   = (float*)(ws + OFF_LS);

    hipMemsetAsync(ws + OFF_BM, 0, 3 * (NE / 8) + 64, stream);

    k_norm_z<<<BATCH, 256, 0, stream>>>(z, zn, rnzt, rnzg);
    k_norm_cb<<<NE, 128, 0, stream>>>(w_st, wsh,        DFULL, rnst);
    k_norm_cb<<<NE, 128, 0, stream>>>(w_sg, wsh + 512,  DFULL, rnsg);
    k_norm_cb<<<NE, 128, 0, stream>>>(w_t,  wt,         DHALF, rnt);
    k_norm_cb<<<NE, 128, 0, stream>>>(w_g,  wg,         DHALF, rng);

    const size_t CD1 = (size_t)BATCH * NCAND;
    dim3 gg(BATCH / 128, NCHUNK);
    k_gemm_topk<<<gg, 256, 0, stream>>>(zn, DFULL, 0,   wsh, DFULL, 16, cd);
    k_gemm_topk<<<gg, 256, 0, stream>>>(zn, DFULL, 0,   wt,  DHALF,  8, cd + CD1);
    k_gemm_topk<<<gg, 256, 0, stream>>>(zn, DFULL, 512, wg,  DHALF,  8, cd + 2 * CD1);

    const size_t O1 = (size_t)BATCH * DFULL;
    const size_t O2 = O1 + (size_t)BATCH * DHALF;
    const size_t O3 = O2 + (size_t)BATCH * DHALF;
    const size_t O4 = O3 + (size_t)BATCH * DHALF;
    const size_t O5 = O4 + (size_t)BATCH * DHALF;

    k_merge<<<BATCH, 256, 0, stream>>>(cd,           w_st, rnst, w_sg, rnsg,
                                       rnzt, rnzg, z, 0,   DFULL,
                                       out,      out + O1, out + O2, bm,               ls);
    k_merge<<<BATCH, 256, 0, stream>>>(cd + CD1,     w_t,  rnt,  nullptr, nullptr,
                                       rnzt, nullptr, z, 0,   DHALF,
                                       out + O3, nullptr,  nullptr,  bm + NE / 32,     ls + 1);
    k_merge<<<BATCH, 256, 0, stream>>>(cd + 2 * CD1, w_g,  rng,  nullptr, nullptr,
                                       rnzg, nullptr, z, 512, DHALF,
                                       out + O4, nullptr,  nullptr,  bm + 2 * (NE / 32), ls + 2);

    k_scalars<<<1, 256, 0, stream>>>(bm, ls, out + O5);
}